// Round 1
// baseline (642.671 us; speedup 1.0000x reference)
//
#include <hip/hip_runtime.h>
#include <hip/hip_bf16.h>
#include <stdint.h>

// Problem constants
#define DIM   1024
#define HID   2732
#define HPAD  2816            // HID padded to multiple of 128 (zero-filled)
#define NEXP  8
#define NTOK  4096            // B*S
#define NROW  8192            // NTOK * TOPK

typedef __attribute__((ext_vector_type(8))) short bf16x8;   // 8 bf16 = 4 VGPRs
typedef __attribute__((ext_vector_type(4))) float f32x4;

__device__ __forceinline__ unsigned short f2bf(float f) {
    union { float f; uint32_t u; } v; v.f = f;
    uint32_t u = v.u;
    return (unsigned short)((u + 0x7FFFu + ((u >> 16) & 1u)) >> 16);  // RNE
}

#define ASYNC_CP16(g, l) __builtin_amdgcn_global_load_lds( \
    (const __attribute__((address_space(1))) void*)(g), \
    (__attribute__((address_space(3))) void*)(l), 16, 0, 0)

// ---------------- weight conversion -------------------------------------
// W1/W3: src [E][HID][DIM] f32 -> dst [E][HPAD][DIM] bf16 (rows >= HID zero)
__global__ void conv_w13_kernel(const float* __restrict__ src,
                                unsigned short* __restrict__ dst) {
    size_t t = (size_t)blockIdx.x * 256 + threadIdx.x;   // 4 elems along D each
    int d4 = (int)(t & 255);                             // DIM/4 = 256
    size_t rest = t >> 8;
    int hp = (int)(rest % HPAD);
    int e  = (int)(rest / HPAD);
    ushort4 o;
    if (hp < HID) {
        float4 v = *(const float4*)(src + ((size_t)e * HID + hp) * DIM + d4 * 4);
        o.x = f2bf(v.x); o.y = f2bf(v.y); o.z = f2bf(v.z); o.w = f2bf(v.w);
    } else {
        o.x = o.y = o.z = o.w = 0;
    }
    *(ushort4*)(dst + t * 4) = o;
}

// W2: src [E][DIM][HID] f32 -> dst [E][DIM][HPAD] bf16 (cols >= HID zero)
__global__ void conv_w2_kernel(const float* __restrict__ src,
                               unsigned short* __restrict__ dst) {
    size_t t = (size_t)blockIdx.x * 256 + threadIdx.x;   // 4 elems along HPAD
    int h4 = (int)(t % (HPAD / 4));                      // 704
    size_t rest = t / (HPAD / 4);
    int d = (int)(rest % DIM);
    int e = (int)(rest / DIM);
    ushort4 o;
    if (h4 * 4 < HID) {                                  // HID%4==0: group all-in or all-out
        float4 v = *(const float4*)(src + ((size_t)e * DIM + d) * HID + h4 * 4);
        o.x = f2bf(v.x); o.y = f2bf(v.y); o.z = f2bf(v.z); o.w = f2bf(v.w);
    } else {
        o.x = o.y = o.z = o.w = 0;
    }
    *(ushort4*)(dst + t * 4) = o;
}

// ---------------- routing ------------------------------------------------
__global__ void route_kernel(const float* __restrict__ x, const float* __restrict__ Wg,
                             int* __restrict__ counts, int* __restrict__ a_exp,
                             int* __restrict__ a_rank, float* __restrict__ a_w) {
    int wave = threadIdx.x >> 6, lane = threadIdx.x & 63;
    int n = blockIdx.x * 4 + wave;
    const float* xr = x + (size_t)n * DIM + lane * 16;
    float p[NEXP];
#pragma unroll
    for (int e = 0; e < NEXP; ++e) p[e] = 0.f;
#pragma unroll
    for (int i = 0; i < 4; ++i) {
        float4 xv = *(const float4*)(xr + i * 4);
#pragma unroll
        for (int e = 0; e < NEXP; ++e) {
            float4 wv = *(const float4*)(Wg + e * DIM + lane * 16 + i * 4);
            p[e] += xv.x * wv.x + xv.y * wv.y + xv.z * wv.z + xv.w * wv.w;
        }
    }
#pragma unroll
    for (int off = 32; off > 0; off >>= 1)
#pragma unroll
        for (int e = 0; e < NEXP; ++e) p[e] += __shfl_xor(p[e], off);
    if (lane == 0) {
        int i1 = -1, i2 = -1; float m1 = -1e30f, m2 = -1e30f;
#pragma unroll
        for (int e = 0; e < NEXP; ++e) {
            float s = p[e];
            if (s > m1) { m2 = m1; i2 = i1; m1 = s; i1 = e; }
            else if (s > m2) { m2 = s; i2 = e; }
        }
        float e2 = __expf(m2 - m1);           // <= 1
        float inv = 1.f / (1.f + e2);
        int a = n * 2;
        a_exp[a] = i1;  a_w[a] = inv;        a_rank[a] = atomicAdd(&counts[i1], 1);
        a_exp[a+1] = i2; a_w[a+1] = e2 * inv; a_rank[a+1] = atomicAdd(&counts[i2], 1);
    }
}

__global__ void scan_kernel(const int* __restrict__ counts, int* __restrict__ offsets) {
    if (threadIdx.x == 0) {
        int s = 0;
        for (int e = 0; e < NEXP; ++e) { offsets[e] = s; s += counts[e]; }
    }
}

// gather x rows into per-expert contiguous bf16 buffer; one block per assignment
__global__ void gather_kernel(const float* __restrict__ x, const int* __restrict__ a_exp,
                              const int* __restrict__ a_rank, const float* __restrict__ a_w,
                              const int* __restrict__ offsets,
                              unsigned short* __restrict__ XG,
                              int* __restrict__ tok_of_row, float* __restrict__ wgt_of_row) {
    int a = blockIdx.x, n = a >> 1;
    int row = offsets[a_exp[a]] + a_rank[a];
    if (threadIdx.x == 0) { tok_of_row[row] = n; wgt_of_row[row] = a_w[a]; }
    float4 xv = *(const float4*)(x + (size_t)n * DIM + threadIdx.x * 4);
    ushort4 o; o.x = f2bf(xv.x); o.y = f2bf(xv.y); o.z = f2bf(xv.z); o.w = f2bf(xv.w);
    *(ushort4*)(XG + (size_t)row * DIM + threadIdx.x * 4) = o;
}

// ---------------- GEMM1: h = silu(x W1^T) * (x W3^T) ---------------------
// Block tile 128(M) x 64(N), BK=64. 4 waves, each 64x32, dual accumulators.
__global__ __launch_bounds__(256, 2) void gemm1_kernel(
    const unsigned short* __restrict__ XG,   // [NROW][DIM]
    const unsigned short* __restrict__ W1b,  // [E][HPAD][DIM]
    const unsigned short* __restrict__ W3b,
    const int* __restrict__ counts, const int* __restrict__ offsets,
    unsigned short* __restrict__ Hbuf)       // [NROW][HPAD]
{
    const int e = blockIdx.z, mtile = blockIdx.y, ntile = blockIdx.x;
    const int cnt = counts[e];
    if (mtile * 128 >= cnt) return;
    const int rowstart = offsets[e] + mtile * 128;

    __shared__ __align__(16) unsigned short As[128 * 64];
    __shared__ __align__(16) unsigned short B1s[64 * 64];
    __shared__ __align__(16) unsigned short B3s[64 * 64];

    const int tid = threadIdx.x, lane = tid & 63, wave = tid >> 6;
    const int wm = wave >> 1, wn = wave & 1;
    const int quad = lane >> 4;

    const unsigned short* w1e = W1b + (size_t)e * HPAD * DIM;
    const unsigned short* w3e = W3b + (size_t)e * HPAD * DIM;

    // staging base pointers (element offsets); col chunk = (tid&7)*8, row = tid>>3
    const int srow = tid >> 3, scol = (tid & 7) * 8;
    const unsigned short* ag[4];
#pragma unroll
    for (int r = 0; r < 4; ++r) {
        int grow = rowstart + r * 32 + srow;
        if (grow > NROW - 1) grow = NROW - 1;         // clamp: junk rows discarded at store
        ag[r] = XG + (size_t)grow * DIM + scol;
    }
    const unsigned short* bg1[2]; const unsigned short* bg3[2];
#pragma unroll
    for (int r = 0; r < 2; ++r) {
        int grow = ntile * 64 + r * 32 + srow;
        bg1[r] = w1e + (size_t)grow * DIM + scol;
        bg3[r] = w3e + (size_t)grow * DIM + scol;
    }

    f32x4 acc1[4][2], acc3[4][2];
#pragma unroll
    for (int i = 0; i < 4; ++i)
#pragma unroll
        for (int j = 0; j < 2; ++j) {
            acc1[i][j] = (f32x4){0.f, 0.f, 0.f, 0.f};
            acc3[i][j] = (f32x4){0.f, 0.f, 0.f, 0.f};
        }

    for (int kk = 0; kk < DIM / 64; ++kk) {
        const int k0 = kk * 64;
#pragma unroll
        for (int r = 0; r < 4; ++r)
            ASYNC_CP16(ag[r] + k0, &As[r * 2048 + tid * 8]);
#pragma unroll
        for (int r = 0; r < 2; ++r) {
            ASYNC_CP16(bg1[r] + k0, &B1s[r * 2048 + tid * 8]);
            ASYNC_CP16(bg3[r] + k0, &B3s[r * 2048 + tid * 8]);
        }
        __syncthreads();
#pragma unroll
        for (int ks = 0; ks < 2; ++ks) {
            const int krd = ks * 32 + quad * 8;
            bf16x8 af[4], b1f[2], b3f[2];
#pragma unroll
            for (int i = 0; i < 4; ++i)
                af[i] = *(const bf16x8*)&As[(wm * 64 + i * 16 + (lane & 15)) * 64 + krd];
#pragma unroll
            for (int j = 0; j < 2; ++j) {
                b1f[j] = *(const bf16x8*)&B1s[(wn * 32 + j * 16 + (lane & 15)) * 64 + krd];
                b3f[j] = *(const bf16x8*)&B3s[(wn * 32 + j * 16 + (lane & 15)) * 64 + krd];
            }
#pragma unroll
            for (int i = 0; i < 4; ++i)
#pragma unroll
                for (int j = 0; j < 2; ++j) {
                    acc1[i][j] = __builtin_amdgcn_mfma_f32_16x16x32_bf16(af[i], b1f[j], acc1[i][j], 0, 0, 0);
                    acc3[i][j] = __builtin_amdgcn_mfma_f32_16x16x32_bf16(af[i], b3f[j], acc3[i][j], 0, 0, 0);
                }
        }
        __syncthreads();
    }

    int mvalid = cnt - mtile * 128; if (mvalid > 128) mvalid = 128;
#pragma unroll
    for (int i = 0; i < 4; ++i)
#pragma unroll
        for (int r = 0; r < 4; ++r) {
            int rl = wm * 64 + i * 16 + quad * 4 + r;
            if (rl < mvalid) {
                size_t rowg = (size_t)(rowstart + rl);
#pragma unroll
                for (int j = 0; j < 2; ++j) {
                    float v1 = acc1[i][j][r], v3 = acc3[i][j][r];
                    float s = v1 / (1.f + __expf(-v1));      // silu
                    Hbuf[rowg * HPAD + ntile * 64 + wn * 32 + j * 16 + (lane & 15)] = f2bf(s * v3);
                }
            }
        }
}

// ---------------- GEMM2: y = h W2^T ; out[tok] += w * y ------------------
// Block tile 128(M) x 128(N), BK=64, K=HPAD. 4 waves, each 64x64.
__global__ __launch_bounds__(256, 2) void gemm2_kernel(
    const unsigned short* __restrict__ Hbuf, // [NROW][HPAD]
    const unsigned short* __restrict__ W2b,  // [E][DIM][HPAD]
    const int* __restrict__ counts, const int* __restrict__ offsets,
    const int* __restrict__ tok_of_row, const float* __restrict__ wgt_of_row,
    float* __restrict__ out)                 // [NTOK][DIM]
{
    const int e = blockIdx.z, mtile = blockIdx.y, ntile = blockIdx.x;
    const int cnt = counts[e];
    if (mtile * 128 >= cnt) return;
    const int rowstart = offsets[e] + mtile * 128;

    __shared__ __align__(16) unsigned short As[128 * 64];
    __shared__ __align__(16) unsigned short Bs[128 * 64];

    const int tid = threadIdx.x, lane = tid & 63, wave = tid >> 6;
    const int wm = wave >> 1, wn = wave & 1;
    const int quad = lane >> 4;

    const unsigned short* w2e = W2b + (size_t)e * DIM * HPAD;
    const int srow = tid >> 3, scol = (tid & 7) * 8;
    const unsigned short* ag[4]; const unsigned short* bg[4];
#pragma unroll
    for (int r = 0; r < 4; ++r) {
        int grow = rowstart + r * 32 + srow;
        if (grow > NROW - 1) grow = NROW - 1;
        ag[r] = Hbuf + (size_t)grow * HPAD + scol;
        bg[r] = w2e + (size_t)(ntile * 128 + r * 32 + srow) * HPAD + scol;
    }

    f32x4 acc[4][4];
#pragma unroll
    for (int i = 0; i < 4; ++i)
#pragma unroll
        for (int j = 0; j < 4; ++j) acc[i][j] = (f32x4){0.f, 0.f, 0.f, 0.f};

    for (int kk = 0; kk < HPAD / 64; ++kk) {
        const int k0 = kk * 64;
#pragma unroll
        for (int r = 0; r < 4; ++r) {
            ASYNC_CP16(ag[r] + k0, &As[r * 2048 + tid * 8]);
            ASYNC_CP16(bg[r] + k0, &Bs[r * 2048 + tid * 8]);
        }
        __syncthreads();
#pragma unroll
        for (int ks = 0; ks < 2; ++ks) {
            const int krd = ks * 32 + quad * 8;
            bf16x8 af[4], bf[4];
#pragma unroll
            for (int i = 0; i < 4; ++i) {
                af[i] = *(const bf16x8*)&As[(wm * 64 + i * 16 + (lane & 15)) * 64 + krd];
                bf[i] = *(const bf16x8*)&Bs[(wn * 64 + i * 16 + (lane & 15)) * 64 + krd];
            }
#pragma unroll
            for (int i = 0; i < 4; ++i)
#pragma unroll
                for (int j = 0; j < 4; ++j)
                    acc[i][j] = __builtin_amdgcn_mfma_f32_16x16x32_bf16(af[i], bf[j], acc[i][j], 0, 0, 0);
        }
        __syncthreads();
    }

    int mvalid = cnt - mtile * 128; if (mvalid > 128) mvalid = 128;
#pragma unroll
    for (int i = 0; i < 4; ++i)
#pragma unroll
        for (int r = 0; r < 4; ++r) {
            int rl = wm * 64 + i * 16 + quad * 4 + r;
            if (rl < mvalid) {
                int rowg = rowstart + rl;
                int tok = tok_of_row[rowg];
                float wt = wgt_of_row[rowg];
                float* orow = out + (size_t)tok * DIM + ntile * 128 + wn * 64 + (lane & 15);
#pragma unroll
                for (int j = 0; j < 4; ++j)
                    atomicAdd(orow + j * 16, acc[i][j][r] * wt);
            }
        }
}

// ---------------- launch -------------------------------------------------
extern "C" void kernel_launch(void* const* d_in, const int* in_sizes, int n_in,
                              void* d_out, int out_size, void* d_ws, size_t ws_size,
                              hipStream_t stream) {
    const float* x  = (const float*)d_in[0];
    const float* Wg = (const float*)d_in[1];
    const float* W1 = (const float*)d_in[2];
    const float* W2 = (const float*)d_in[3];
    const float* W3 = (const float*)d_in[4];
    float* out = (float*)d_out;

    char* ws = (char*)d_ws;
    size_t off = 0;
    auto alloc = [&](size_t bytes) -> void* {
        void* p = ws + off;
        off = (off + bytes + 255) & ~(size_t)255;
        return p;
    };
    int*   counts      = (int*)alloc(NEXP * 4);
    int*   offsets     = (int*)alloc(NEXP * 4);
    int*   a_exp       = (int*)alloc(NROW * 4);
    int*   a_rank      = (int*)alloc(NROW * 4);
    float* a_w         = (float*)alloc(NROW * 4);
    int*   tok_of_row  = (int*)alloc(NROW * 4);
    float* wgt_of_row  = (float*)alloc(NROW * 4);
    unsigned short* XG   = (unsigned short*)alloc((size_t)NROW * DIM * 2);
    unsigned short* Hbuf = (unsigned short*)alloc((size_t)NROW * HPAD * 2);
    unsigned short* W1b  = (unsigned short*)alloc((size_t)NEXP * HPAD * DIM * 2);
    unsigned short* W3b  = (unsigned short*)alloc((size_t)NEXP * HPAD * DIM * 2);
    unsigned short* W2b  = (unsigned short*)alloc((size_t)NEXP * DIM * HPAD * 2);

    hipMemsetAsync(counts, 0, NEXP * 4, stream);
    hipMemsetAsync(out, 0, (size_t)out_size * 4, stream);

    const int convBlocks = (NEXP * HPAD * DIM / 4) / 256;   // 22528
    conv_w13_kernel<<<convBlocks, 256, 0, stream>>>(W1, W1b);
    conv_w13_kernel<<<convBlocks, 256, 0, stream>>>(W3, W3b);
    conv_w2_kernel<<<convBlocks, 256, 0, stream>>>(W2, W2b);

    route_kernel<<<NTOK / 4, 256, 0, stream>>>(x, Wg, counts, a_exp, a_rank, a_w);
    scan_kernel<<<1, 64, 0, stream>>>(counts, offsets);
    gather_kernel<<<NROW, 256, 0, stream>>>(x, a_exp, a_rank, a_w, offsets,
                                            XG, tok_of_row, wgt_of_row);

    gemm1_kernel<<<dim3(HPAD / 64, 32, NEXP), 256, 0, stream>>>(
        XG, W1b, W3b, counts, offsets, Hbuf);
    gemm2_kernel<<<dim3(DIM / 128, 32, NEXP), 256, 0, stream>>>(
        Hbuf, W2b, counts, offsets, tok_of_row, wgt_of_row, out);
}

// Round 2
// 597.390 us; speedup vs baseline: 1.0758x; 1.0758x over previous
//
#include <hip/hip_runtime.h>
#include <hip/hip_bf16.h>
#include <stdint.h>

// Problem constants
#define DIM   1024
#define HID   2732
#define HPAD  2816            // HID padded to multiple of 128 (zero-filled)
#define NEXP  8
#define NTOK  4096            // B*S
#define NROW  8192            // NTOK * TOPK

typedef __attribute__((ext_vector_type(8))) short bf16x8;   // 8 bf16 = 4 VGPRs
typedef __attribute__((ext_vector_type(4))) float f32x4;

__device__ __forceinline__ unsigned short f2bf(float f) {
    union { float f; uint32_t u; } v; v.f = f;
    uint32_t u = v.u;
    return (unsigned short)((u + 0x7FFFu + ((u >> 16) & 1u)) >> 16);  // RNE
}

#define ASYNC_CP16(g, l) __builtin_amdgcn_global_load_lds( \
    (const __attribute__((address_space(1))) void*)(g), \
    (__attribute__((address_space(3))) void*)(l), 16, 0, 0)

// ---------------- weight conversion -------------------------------------
// W1/W3: src [E][HID][DIM] f32 -> dst [E][HPAD][DIM] bf16 (rows >= HID zero)
__global__ void conv_w13_kernel(const float* __restrict__ src,
                                unsigned short* __restrict__ dst) {
    size_t t = (size_t)blockIdx.x * 256 + threadIdx.x;   // 4 elems along D each
    int d4 = (int)(t & 255);                             // DIM/4 = 256
    size_t rest = t >> 8;
    int hp = (int)(rest % HPAD);
    int e  = (int)(rest / HPAD);
    ushort4 o;
    if (hp < HID) {
        float4 v = *(const float4*)(src + ((size_t)e * HID + hp) * DIM + d4 * 4);
        o.x = f2bf(v.x); o.y = f2bf(v.y); o.z = f2bf(v.z); o.w = f2bf(v.w);
    } else {
        o.x = o.y = o.z = o.w = 0;
    }
    *(ushort4*)(dst + t * 4) = o;
}

// W2: src [E][DIM][HID] f32 -> dst [E][DIM][HPAD] bf16 (cols >= HID zero)
__global__ void conv_w2_kernel(const float* __restrict__ src,
                               unsigned short* __restrict__ dst) {
    size_t t = (size_t)blockIdx.x * 256 + threadIdx.x;   // 4 elems along HPAD
    int h4 = (int)(t % (HPAD / 4));                      // 704
    size_t rest = t / (HPAD / 4);
    int d = (int)(rest % DIM);
    int e = (int)(rest / DIM);
    ushort4 o;
    if (h4 * 4 < HID) {                                  // HID%4==0: group all-in or all-out
        float4 v = *(const float4*)(src + ((size_t)e * DIM + d) * HID + h4 * 4);
        o.x = f2bf(v.x); o.y = f2bf(v.y); o.z = f2bf(v.z); o.w = f2bf(v.w);
    } else {
        o.x = o.y = o.z = o.w = 0;
    }
    *(ushort4*)(dst + t * 4) = o;
}

// ---------------- routing ------------------------------------------------
__global__ void route_kernel(const float* __restrict__ x, const float* __restrict__ Wg,
                             int* __restrict__ counts, int* __restrict__ a_exp,
                             int* __restrict__ a_rank, float* __restrict__ a_w) {
    int wave = threadIdx.x >> 6, lane = threadIdx.x & 63;
    int n = blockIdx.x * 4 + wave;
    const float* xr = x + (size_t)n * DIM + lane * 16;
    float p[NEXP];
#pragma unroll
    for (int e = 0; e < NEXP; ++e) p[e] = 0.f;
#pragma unroll
    for (int i = 0; i < 4; ++i) {
        float4 xv = *(const float4*)(xr + i * 4);
#pragma unroll
        for (int e = 0; e < NEXP; ++e) {
            float4 wv = *(const float4*)(Wg + e * DIM + lane * 16 + i * 4);
            p[e] += xv.x * wv.x + xv.y * wv.y + xv.z * wv.z + xv.w * wv.w;
        }
    }
#pragma unroll
    for (int off = 32; off > 0; off >>= 1)
#pragma unroll
        for (int e = 0; e < NEXP; ++e) p[e] += __shfl_xor(p[e], off);
    if (lane == 0) {
        int i1 = -1, i2 = -1; float m1 = -1e30f, m2 = -1e30f;
#pragma unroll
        for (int e = 0; e < NEXP; ++e) {
            float s = p[e];
            if (s > m1) { m2 = m1; i2 = i1; m1 = s; i1 = e; }
            else if (s > m2) { m2 = s; i2 = e; }
        }
        float e2 = __expf(m2 - m1);           // <= 1
        float inv = 1.f / (1.f + e2);
        int a = n * 2;
        a_exp[a] = i1;  a_w[a] = inv;        a_rank[a] = atomicAdd(&counts[i1], 1);
        a_exp[a+1] = i2; a_w[a+1] = e2 * inv; a_rank[a+1] = atomicAdd(&counts[i2], 1);
    }
}

__global__ void scan_kernel(const int* __restrict__ counts, int* __restrict__ offsets) {
    if (threadIdx.x == 0) {
        int s = 0;
        for (int e = 0; e < NEXP; ++e) { offsets[e] = s; s += counts[e]; }
    }
}

// gather x rows into per-expert contiguous bf16 buffer; one block per assignment
__global__ void gather_kernel(const float* __restrict__ x, const int* __restrict__ a_exp,
                              const int* __restrict__ a_rank,
                              const int* __restrict__ offsets,
                              unsigned short* __restrict__ XG,
                              int* __restrict__ row_of_a) {
    int a = blockIdx.x, n = a >> 1;
    int row = offsets[a_exp[a]] + a_rank[a];
    if (threadIdx.x == 0) row_of_a[a] = row;
    float4 xv = *(const float4*)(x + (size_t)n * DIM + threadIdx.x * 4);
    ushort4 o; o.x = f2bf(xv.x); o.y = f2bf(xv.y); o.z = f2bf(xv.z); o.w = f2bf(xv.w);
    *(ushort4*)(XG + (size_t)row * DIM + threadIdx.x * 4) = o;
}

// ---------------- GEMM1: h = silu(x W1^T) * (x W3^T) ---------------------
// Block tile 128(M) x 64(N), BK=64. 4 waves, each 64x32, dual accumulators.
// LDS XOR-swizzle: global chunk c of tile-row r is stored at chunk slot
// c ^ (r&7). Staging permutes the global source column (dest must stay
// wave-uniform+lane*16 for global_load_lds); readers XOR the chunk index.
__global__ __launch_bounds__(256, 2) void gemm1_kernel(
    const unsigned short* __restrict__ XG,   // [NROW][DIM]
    const unsigned short* __restrict__ W1b,  // [E][HPAD][DIM]
    const unsigned short* __restrict__ W3b,
    const int* __restrict__ counts, const int* __restrict__ offsets,
    unsigned short* __restrict__ Hbuf)       // [NROW][HPAD]
{
    const int e = blockIdx.z, mtile = blockIdx.y, ntile = blockIdx.x;
    const int cnt = counts[e];
    if (mtile * 128 >= cnt) return;
    const int rowstart = offsets[e] + mtile * 128;

    __shared__ __align__(16) unsigned short As[128 * 64];
    __shared__ __align__(16) unsigned short B1s[64 * 64];
    __shared__ __align__(16) unsigned short B3s[64 * 64];

    const int tid = threadIdx.x, lane = tid & 63, wave = tid >> 6;
    const int wm = wave >> 1, wn = wave & 1;
    const int quad = lane >> 4;

    const unsigned short* w1e = W1b + (size_t)e * HPAD * DIM;
    const unsigned short* w3e = W3b + (size_t)e * HPAD * DIM;

    // staging: srow = tid>>3 (row within 32-row chunk), swizzled source col
    const int srow = tid >> 3;
    const int scol = (((tid & 7) ^ (srow & 7)) * 8);
    const unsigned short* ag[4];
#pragma unroll
    for (int r = 0; r < 4; ++r) {
        int grow = rowstart + r * 32 + srow;
        if (grow > NROW - 1) grow = NROW - 1;         // clamp: junk rows discarded at store
        ag[r] = XG + (size_t)grow * DIM + scol;
    }
    const unsigned short* bg1[2]; const unsigned short* bg3[2];
#pragma unroll
    for (int r = 0; r < 2; ++r) {
        int grow = ntile * 64 + r * 32 + srow;
        bg1[r] = w1e + (size_t)grow * DIM + scol;
        bg3[r] = w3e + (size_t)grow * DIM + scol;
    }

    f32x4 acc1[4][2], acc3[4][2];
#pragma unroll
    for (int i = 0; i < 4; ++i)
#pragma unroll
        for (int j = 0; j < 2; ++j) {
            acc1[i][j] = (f32x4){0.f, 0.f, 0.f, 0.f};
            acc3[i][j] = (f32x4){0.f, 0.f, 0.f, 0.f};
        }

    for (int kk = 0; kk < DIM / 64; ++kk) {
        const int k0 = kk * 64;
#pragma unroll
        for (int r = 0; r < 4; ++r)
            ASYNC_CP16(ag[r] + k0, &As[r * 2048 + tid * 8]);
#pragma unroll
        for (int r = 0; r < 2; ++r) {
            ASYNC_CP16(bg1[r] + k0, &B1s[r * 2048 + tid * 8]);
            ASYNC_CP16(bg3[r] + k0, &B3s[r * 2048 + tid * 8]);
        }
        __syncthreads();
#pragma unroll
        for (int ks = 0; ks < 2; ++ks) {
            const int cbase = ks * 4 + quad;            // chunk index 0..7
            bf16x8 af[4], b1f[2], b3f[2];
#pragma unroll
            for (int i = 0; i < 4; ++i) {
                int rl = wm * 64 + i * 16 + (lane & 15);
                af[i] = *(const bf16x8*)&As[rl * 64 + ((cbase ^ (rl & 7)) * 8)];
            }
#pragma unroll
            for (int j = 0; j < 2; ++j) {
                int rl1 = wn * 32 + j * 16 + (lane & 15);
                b1f[j] = *(const bf16x8*)&B1s[rl1 * 64 + ((cbase ^ (rl1 & 7)) * 8)];
                b3f[j] = *(const bf16x8*)&B3s[rl1 * 64 + ((cbase ^ (rl1 & 7)) * 8)];
            }
#pragma unroll
            for (int i = 0; i < 4; ++i)
#pragma unroll
                for (int j = 0; j < 2; ++j) {
                    acc1[i][j] = __builtin_amdgcn_mfma_f32_16x16x32_bf16(af[i], b1f[j], acc1[i][j], 0, 0, 0);
                    acc3[i][j] = __builtin_amdgcn_mfma_f32_16x16x32_bf16(af[i], b3f[j], acc3[i][j], 0, 0, 0);
                }
        }
        __syncthreads();
    }

    int mvalid = cnt - mtile * 128; if (mvalid > 128) mvalid = 128;
#pragma unroll
    for (int i = 0; i < 4; ++i)
#pragma unroll
        for (int r = 0; r < 4; ++r) {
            int rl = wm * 64 + i * 16 + quad * 4 + r;
            if (rl < mvalid) {
                size_t rowg = (size_t)(rowstart + rl);
#pragma unroll
                for (int j = 0; j < 2; ++j) {
                    float v1 = acc1[i][j][r], v3 = acc3[i][j][r];
                    float s = v1 / (1.f + __expf(-v1));      // silu
                    Hbuf[rowg * HPAD + ntile * 64 + wn * 32 + j * 16 + (lane & 15)] = f2bf(s * v3);
                }
            }
        }
}

// ---------------- GEMM2: y = h W2^T -> Ybuf (f32, unscaled) --------------
// Block tile 128(M) x 128(N), BK=64, K=HPAD. 4 waves, each 64x64.
__global__ __launch_bounds__(256, 2) void gemm2_kernel(
    const unsigned short* __restrict__ Hbuf, // [NROW][HPAD]
    const unsigned short* __restrict__ W2b,  // [E][DIM][HPAD]
    const int* __restrict__ counts, const int* __restrict__ offsets,
    float* __restrict__ Ybuf)                // [NROW][DIM]
{
    const int e = blockIdx.z, mtile = blockIdx.y, ntile = blockIdx.x;
    const int cnt = counts[e];
    if (mtile * 128 >= cnt) return;
    const int rowstart = offsets[e] + mtile * 128;

    __shared__ __align__(16) unsigned short As[128 * 64];
    __shared__ __align__(16) unsigned short Bs[128 * 64];

    const int tid = threadIdx.x, lane = tid & 63, wave = tid >> 6;
    const int wm = wave >> 1, wn = wave & 1;
    const int quad = lane >> 4;

    const unsigned short* w2e = W2b + (size_t)e * DIM * HPAD;
    const int srow = tid >> 3;
    const int scol = (((tid & 7) ^ (srow & 7)) * 8);
    const unsigned short* ag[4]; const unsigned short* bg[4];
#pragma unroll
    for (int r = 0; r < 4; ++r) {
        int grow = rowstart + r * 32 + srow;
        if (grow > NROW - 1) grow = NROW - 1;
        ag[r] = Hbuf + (size_t)grow * HPAD + scol;
        bg[r] = w2e + (size_t)(ntile * 128 + r * 32 + srow) * HPAD + scol;
    }

    f32x4 acc[4][4];
#pragma unroll
    for (int i = 0; i < 4; ++i)
#pragma unroll
        for (int j = 0; j < 4; ++j) acc[i][j] = (f32x4){0.f, 0.f, 0.f, 0.f};

    for (int kk = 0; kk < HPAD / 64; ++kk) {
        const int k0 = kk * 64;
#pragma unroll
        for (int r = 0; r < 4; ++r) {
            ASYNC_CP16(ag[r] + k0, &As[r * 2048 + tid * 8]);
            ASYNC_CP16(bg[r] + k0, &Bs[r * 2048 + tid * 8]);
        }
        __syncthreads();
#pragma unroll
        for (int ks = 0; ks < 2; ++ks) {
            const int cbase = ks * 4 + quad;
            bf16x8 af[4], bf[4];
#pragma unroll
            for (int i = 0; i < 4; ++i) {
                int rla = wm * 64 + i * 16 + (lane & 15);
                int rlb = wn * 64 + i * 16 + (lane & 15);
                af[i] = *(const bf16x8*)&As[rla * 64 + ((cbase ^ (rla & 7)) * 8)];
                bf[i] = *(const bf16x8*)&Bs[rlb * 64 + ((cbase ^ (rlb & 7)) * 8)];
            }
#pragma unroll
            for (int i = 0; i < 4; ++i)
#pragma unroll
                for (int j = 0; j < 4; ++j)
                    acc[i][j] = __builtin_amdgcn_mfma_f32_16x16x32_bf16(af[i], bf[j], acc[i][j], 0, 0, 0);
        }
        __syncthreads();
    }

    int mvalid = cnt - mtile * 128; if (mvalid > 128) mvalid = 128;
#pragma unroll
    for (int i = 0; i < 4; ++i)
#pragma unroll
        for (int r = 0; r < 4; ++r) {
            int rl = wm * 64 + i * 16 + quad * 4 + r;
            if (rl < mvalid) {
                int rowg = rowstart + rl;
                float* yrow = Ybuf + (size_t)rowg * DIM + ntile * 128 + wn * 64 + (lane & 15);
#pragma unroll
                for (int j = 0; j < 4; ++j)
                    yrow[j * 16] = acc[i][j][r];
            }
        }
}

// ---------------- combine: out[n] = w0*Y[row0] + w1*Y[row1] --------------
__global__ void combine_kernel(const float* __restrict__ Ybuf,
                               const int* __restrict__ row_of_a,
                               const float* __restrict__ a_w,
                               float* __restrict__ out) {
    int n = blockIdx.x, t = threadIdx.x;                 // 256 threads, DIM/4
    int r0 = row_of_a[2 * n], r1 = row_of_a[2 * n + 1];
    float w0 = a_w[2 * n], w1 = a_w[2 * n + 1];
    float4 y0 = *(const float4*)(Ybuf + (size_t)r0 * DIM + t * 4);
    float4 y1 = *(const float4*)(Ybuf + (size_t)r1 * DIM + t * 4);
    float4 o;
    o.x = w0 * y0.x + w1 * y1.x;
    o.y = w0 * y0.y + w1 * y1.y;
    o.z = w0 * y0.z + w1 * y1.z;
    o.w = w0 * y0.w + w1 * y1.w;
    *(float4*)(out + (size_t)n * DIM + t * 4) = o;
}

// ---------------- launch -------------------------------------------------
extern "C" void kernel_launch(void* const* d_in, const int* in_sizes, int n_in,
                              void* d_out, int out_size, void* d_ws, size_t ws_size,
                              hipStream_t stream) {
    const float* x  = (const float*)d_in[0];
    const float* Wg = (const float*)d_in[1];
    const float* W1 = (const float*)d_in[2];
    const float* W2 = (const float*)d_in[3];
    const float* W3 = (const float*)d_in[4];
    float* out = (float*)d_out;

    char* ws = (char*)d_ws;
    size_t off = 0;
    auto alloc = [&](size_t bytes) -> void* {
        void* p = ws + off;
        off = (off + bytes + 255) & ~(size_t)255;
        return p;
    };
    int*   counts      = (int*)alloc(NEXP * 4);
    int*   offsets     = (int*)alloc(NEXP * 4);
    int*   a_exp       = (int*)alloc(NROW * 4);
    int*   a_rank      = (int*)alloc(NROW * 4);
    float* a_w         = (float*)alloc(NROW * 4);
    int*   row_of_a    = (int*)alloc(NROW * 4);
    unsigned short* XG   = (unsigned short*)alloc((size_t)NROW * DIM * 2);
    unsigned short* Hbuf = (unsigned short*)alloc((size_t)NROW * HPAD * 2);
    unsigned short* W1b  = (unsigned short*)alloc((size_t)NEXP * HPAD * DIM * 2);
    unsigned short* W3b  = (unsigned short*)alloc((size_t)NEXP * HPAD * DIM * 2);
    unsigned short* W2b  = (unsigned short*)alloc((size_t)NEXP * DIM * HPAD * 2);
    // Ybuf (33.6 MB) aliases W1b (46.1 MB): W1b is dead once gemm1 completes.
    float* Ybuf = (float*)W1b;

    hipMemsetAsync(counts, 0, NEXP * 4, stream);

    const int convBlocks = (NEXP * HPAD * DIM / 4) / 256;   // 22528
    conv_w13_kernel<<<convBlocks, 256, 0, stream>>>(W1, W1b);
    conv_w13_kernel<<<convBlocks, 256, 0, stream>>>(W3, W3b);
    conv_w2_kernel<<<convBlocks, 256, 0, stream>>>(W2, W2b);

    route_kernel<<<NTOK / 4, 256, 0, stream>>>(x, Wg, counts, a_exp, a_rank, a_w);
    scan_kernel<<<1, 64, 0, stream>>>(counts, offsets);
    gather_kernel<<<NROW, 256, 0, stream>>>(x, a_exp, a_rank, offsets, XG, row_of_a);

    gemm1_kernel<<<dim3(HPAD / 64, 64, NEXP), 256, 0, stream>>>(
        XG, W1b, W3b, counts, offsets, Hbuf);
    gemm2_kernel<<<dim3(DIM / 128, 64, NEXP), 256, 0, stream>>>(
        Hbuf, W2b, counts, offsets, Ybuf);
    combine_kernel<<<NTOK, 256, 0, stream>>>(Ybuf, row_of_a, a_w, out);
}

// Round 3
// 575.918 us; speedup vs baseline: 1.1159x; 1.0373x over previous
//
#include <hip/hip_runtime.h>
#include <hip/hip_bf16.h>
#include <stdint.h>

// Problem constants
#define DIM   1024
#define HID   2732
#define HPAD  2816            // HID padded to multiple of 128 (zero-filled)
#define NEXP  8
#define NTOK  4096            // B*S
#define NROW  8192            // NTOK * TOPK
#define C13BLK 22528          // blocks for one W1/W3 conversion (E*HPAD*DIM/4/256)

typedef __attribute__((ext_vector_type(8))) short bf16x8;   // 8 bf16 = 4 VGPRs
typedef __attribute__((ext_vector_type(4))) float f32x4;

__device__ __forceinline__ unsigned short f2bf(float f) {
    union { float f; uint32_t u; } v; v.f = f;
    uint32_t u = v.u;
    return (unsigned short)((u + 0x7FFFu + ((u >> 16) & 1u)) >> 16);  // RNE
}
__device__ __forceinline__ float bf2f(unsigned short h) {
    union { uint32_t u; float f; } v; v.u = ((uint32_t)h) << 16;
    return v.f;
}

#define ASYNC_CP16(g, l) __builtin_amdgcn_global_load_lds( \
    (const __attribute__((address_space(1))) void*)(g), \
    (__attribute__((address_space(3))) void*)(l), 16, 0, 0)

// ---------------- fused prep: 3x weight conversion + routing -------------
// blocks [0,C13BLK)        : W1 f32 [E][HID][DIM] -> W1b bf16 [E][HPAD][DIM]
// blocks [C13BLK,2*C13BLK) : W3 -> W3b
// blocks [2C13,3C13)       : W2 f32 [E][DIM][HID] -> W2b bf16 [E][DIM][HPAD]
// blocks [3C13,3C13+1024)  : routing (4 tokens/block, 1 wave each)
__device__ __forceinline__ void conv13_body(const float* __restrict__ src,
                                            unsigned short* __restrict__ dst, int blk) {
    size_t t = (size_t)blk * 256 + threadIdx.x;          // 4 elems along D each
    int d4 = (int)(t & 255);                             // DIM/4 = 256
    size_t rest = t >> 8;
    int hp = (int)(rest % HPAD);
    int e  = (int)(rest / HPAD);
    ushort4 o;
    if (hp < HID) {
        float4 v = *(const float4*)(src + ((size_t)e * HID + hp) * DIM + d4 * 4);
        o.x = f2bf(v.x); o.y = f2bf(v.y); o.z = f2bf(v.z); o.w = f2bf(v.w);
    } else {
        o.x = o.y = o.z = o.w = 0;
    }
    *(ushort4*)(dst + t * 4) = o;
}

__global__ void prep_kernel(const float* __restrict__ x,  const float* __restrict__ Wg,
                            const float* __restrict__ W1, const float* __restrict__ W2,
                            const float* __restrict__ W3,
                            unsigned short* __restrict__ W1b,
                            unsigned short* __restrict__ W2b,
                            unsigned short* __restrict__ W3b,
                            int* __restrict__ counts, int* __restrict__ a_exp,
                            int* __restrict__ a_rank, float* __restrict__ a_w) {
    int b = blockIdx.x;
    if (b < C13BLK) { conv13_body(W1, W1b, b); return; }
    b -= C13BLK;
    if (b < C13BLK) { conv13_body(W3, W3b, b); return; }
    b -= C13BLK;
    if (b < C13BLK) {
        // W2 conversion
        size_t t = (size_t)b * 256 + threadIdx.x;
        int h4 = (int)(t % (HPAD / 4));                  // 704
        size_t rest = t / (HPAD / 4);
        int d = (int)(rest % DIM);
        int e = (int)(rest / DIM);
        ushort4 o;
        if (h4 * 4 < HID) {
            float4 v = *(const float4*)(W2 + ((size_t)e * DIM + d) * HID + h4 * 4);
            o.x = f2bf(v.x); o.y = f2bf(v.y); o.z = f2bf(v.z); o.w = f2bf(v.w);
        } else {
            o.x = o.y = o.z = o.w = 0;
        }
        *(ushort4*)(W2b + t * 4) = o;
        return;
    }
    b -= C13BLK;
    // routing: block handles 4 tokens, one wave each
    int wave = threadIdx.x >> 6, lane = threadIdx.x & 63;
    int n = b * 4 + wave;
    const float* xr = x + (size_t)n * DIM + lane * 16;
    float p[NEXP];
#pragma unroll
    for (int e = 0; e < NEXP; ++e) p[e] = 0.f;
#pragma unroll
    for (int i = 0; i < 4; ++i) {
        float4 xv = *(const float4*)(xr + i * 4);
#pragma unroll
        for (int e = 0; e < NEXP; ++e) {
            float4 wv = *(const float4*)(Wg + e * DIM + lane * 16 + i * 4);
            p[e] += xv.x * wv.x + xv.y * wv.y + xv.z * wv.z + xv.w * wv.w;
        }
    }
#pragma unroll
    for (int off = 32; off > 0; off >>= 1)
#pragma unroll
        for (int e = 0; e < NEXP; ++e) p[e] += __shfl_xor(p[e], off);
    if (lane == 0) {
        int i1 = -1, i2 = -1; float m1 = -1e30f, m2 = -1e30f;
#pragma unroll
        for (int e = 0; e < NEXP; ++e) {
            float s = p[e];
            if (s > m1) { m2 = m1; i2 = i1; m1 = s; i1 = e; }
            else if (s > m2) { m2 = s; i2 = e; }
        }
        float e2 = __expf(m2 - m1);           // <= 1
        float inv = 1.f / (1.f + e2);
        int a = n * 2;
        a_exp[a] = i1;  a_w[a] = inv;        a_rank[a] = atomicAdd(&counts[i1], 1);
        a_exp[a+1] = i2; a_w[a+1] = e2 * inv; a_rank[a+1] = atomicAdd(&counts[i2], 1);
    }
}

// gather x rows into per-expert contiguous bf16 buffer; one block per assignment.
// Expert offsets recomputed inline from counts (8 ints) — no separate scan pass.
__global__ void gather_kernel(const float* __restrict__ x, const int* __restrict__ a_exp,
                              const int* __restrict__ a_rank,
                              const int* __restrict__ counts,
                              unsigned short* __restrict__ XG,
                              int* __restrict__ row_of_a) {
    __shared__ int soff[NEXP];
    if (threadIdx.x == 0) {
        int s = 0;
#pragma unroll
        for (int e = 0; e < NEXP; ++e) { soff[e] = s; s += counts[e]; }
    }
    __syncthreads();
    int a = blockIdx.x, n = a >> 1;
    int row = soff[a_exp[a]] + a_rank[a];
    if (threadIdx.x == 0) row_of_a[a] = row;
    float4 xv = *(const float4*)(x + (size_t)n * DIM + threadIdx.x * 4);
    ushort4 o; o.x = f2bf(xv.x); o.y = f2bf(xv.y); o.z = f2bf(xv.z); o.w = f2bf(xv.w);
    *(ushort4*)(XG + (size_t)row * DIM + threadIdx.x * 4) = o;
}

// ---------------- GEMM1: h = silu(x W1^T) * (x W3^T) ---------------------
// Block tile 128(M) x 64(N), BK=64. 4 waves, each 64x32, dual accumulators.
// LDS XOR-swizzle: global chunk c of tile-row r stored at chunk slot c^(r&7).
__global__ __launch_bounds__(256, 2) void gemm1_kernel(
    const unsigned short* __restrict__ XG,   // [NROW][DIM]
    const unsigned short* __restrict__ W1b,  // [E][HPAD][DIM]
    const unsigned short* __restrict__ W3b,
    const int* __restrict__ counts,
    unsigned short* __restrict__ Hbuf)       // [NROW][HPAD]
{
    const int e = blockIdx.z, mtile = blockIdx.y, ntile = blockIdx.x;
    const int cnt = counts[e];
    if (mtile * 128 >= cnt) return;
    int rowstart = 0;
    for (int i = 0; i < e; ++i) rowstart += counts[i];
    rowstart += mtile * 128;

    __shared__ __align__(16) unsigned short As[128 * 64];
    __shared__ __align__(16) unsigned short B1s[64 * 64];
    __shared__ __align__(16) unsigned short B3s[64 * 64];

    const int tid = threadIdx.x, lane = tid & 63, wave = tid >> 6;
    const int wm = wave >> 1, wn = wave & 1;
    const int quad = lane >> 4;

    const unsigned short* w1e = W1b + (size_t)e * HPAD * DIM;
    const unsigned short* w3e = W3b + (size_t)e * HPAD * DIM;

    const int srow = tid >> 3;
    const int scol = (((tid & 7) ^ (srow & 7)) * 8);
    const unsigned short* ag[4];
#pragma unroll
    for (int r = 0; r < 4; ++r) {
        int grow = rowstart + r * 32 + srow;
        if (grow > NROW - 1) grow = NROW - 1;         // clamp: junk rows discarded at store
        ag[r] = XG + (size_t)grow * DIM + scol;
    }
    const unsigned short* bg1[2]; const unsigned short* bg3[2];
#pragma unroll
    for (int r = 0; r < 2; ++r) {
        int grow = ntile * 64 + r * 32 + srow;
        bg1[r] = w1e + (size_t)grow * DIM + scol;
        bg3[r] = w3e + (size_t)grow * DIM + scol;
    }

    f32x4 acc1[4][2], acc3[4][2];
#pragma unroll
    for (int i = 0; i < 4; ++i)
#pragma unroll
        for (int j = 0; j < 2; ++j) {
            acc1[i][j] = (f32x4){0.f, 0.f, 0.f, 0.f};
            acc3[i][j] = (f32x4){0.f, 0.f, 0.f, 0.f};
        }

    for (int kk = 0; kk < DIM / 64; ++kk) {
        const int k0 = kk * 64;
#pragma unroll
        for (int r = 0; r < 4; ++r)
            ASYNC_CP16(ag[r] + k0, &As[r * 2048 + tid * 8]);
#pragma unroll
        for (int r = 0; r < 2; ++r) {
            ASYNC_CP16(bg1[r] + k0, &B1s[r * 2048 + tid * 8]);
            ASYNC_CP16(bg3[r] + k0, &B3s[r * 2048 + tid * 8]);
        }
        __syncthreads();
#pragma unroll
        for (int ks = 0; ks < 2; ++ks) {
            const int cbase = ks * 4 + quad;            // chunk index 0..7
            bf16x8 af[4], b1f[2], b3f[2];
#pragma unroll
            for (int i = 0; i < 4; ++i) {
                int rl = wm * 64 + i * 16 + (lane & 15);
                af[i] = *(const bf16x8*)&As[rl * 64 + ((cbase ^ (rl & 7)) * 8)];
            }
#pragma unroll
            for (int j = 0; j < 2; ++j) {
                int rl1 = wn * 32 + j * 16 + (lane & 15);
                b1f[j] = *(const bf16x8*)&B1s[rl1 * 64 + ((cbase ^ (rl1 & 7)) * 8)];
                b3f[j] = *(const bf16x8*)&B3s[rl1 * 64 + ((cbase ^ (rl1 & 7)) * 8)];
            }
#pragma unroll
            for (int i = 0; i < 4; ++i)
#pragma unroll
                for (int j = 0; j < 2; ++j) {
                    acc1[i][j] = __builtin_amdgcn_mfma_f32_16x16x32_bf16(af[i], b1f[j], acc1[i][j], 0, 0, 0);
                    acc3[i][j] = __builtin_amdgcn_mfma_f32_16x16x32_bf16(af[i], b3f[j], acc3[i][j], 0, 0, 0);
                }
        }
        __syncthreads();
    }

    int mvalid = cnt - mtile * 128; if (mvalid > 128) mvalid = 128;
#pragma unroll
    for (int i = 0; i < 4; ++i)
#pragma unroll
        for (int r = 0; r < 4; ++r) {
            int rl = wm * 64 + i * 16 + quad * 4 + r;
            if (rl < mvalid) {
                size_t rowg = (size_t)(rowstart + rl);
#pragma unroll
                for (int j = 0; j < 2; ++j) {
                    float v1 = acc1[i][j][r], v3 = acc3[i][j][r];
                    float s = v1 / (1.f + __expf(-v1));      // silu
                    Hbuf[rowg * HPAD + ntile * 64 + wn * 32 + j * 16 + (lane & 15)] = f2bf(s * v3);
                }
            }
        }
}

// ---------------- GEMM2: y = h W2^T -> Ybuf (bf16, unscaled) -------------
// Block tile 128(M) x 128(N), BK=64, K=HPAD. 4 waves, each 64x64.
__global__ __launch_bounds__(256, 2) void gemm2_kernel(
    const unsigned short* __restrict__ Hbuf, // [NROW][HPAD]
    const unsigned short* __restrict__ W2b,  // [E][DIM][HPAD]
    const int* __restrict__ counts,
    unsigned short* __restrict__ Ybuf)       // [NROW][DIM] bf16
{
    const int e = blockIdx.z, mtile = blockIdx.y, ntile = blockIdx.x;
    const int cnt = counts[e];
    if (mtile * 128 >= cnt) return;
    int rowstart = 0;
    for (int i = 0; i < e; ++i) rowstart += counts[i];
    rowstart += mtile * 128;

    __shared__ __align__(16) unsigned short As[128 * 64];
    __shared__ __align__(16) unsigned short Bs[128 * 64];

    const int tid = threadIdx.x, lane = tid & 63, wave = tid >> 6;
    const int wm = wave >> 1, wn = wave & 1;
    const int quad = lane >> 4;

    const unsigned short* w2e = W2b + (size_t)e * DIM * HPAD;
    const int srow = tid >> 3;
    const int scol = (((tid & 7) ^ (srow & 7)) * 8);
    const unsigned short* ag[4]; const unsigned short* bg[4];
#pragma unroll
    for (int r = 0; r < 4; ++r) {
        int grow = rowstart + r * 32 + srow;
        if (grow > NROW - 1) grow = NROW - 1;
        ag[r] = Hbuf + (size_t)grow * HPAD + scol;
        bg[r] = w2e + (size_t)(ntile * 128 + r * 32 + srow) * HPAD + scol;
    }

    f32x4 acc[4][4];
#pragma unroll
    for (int i = 0; i < 4; ++i)
#pragma unroll
        for (int j = 0; j < 4; ++j) acc[i][j] = (f32x4){0.f, 0.f, 0.f, 0.f};

    for (int kk = 0; kk < HPAD / 64; ++kk) {
        const int k0 = kk * 64;
#pragma unroll
        for (int r = 0; r < 4; ++r) {
            ASYNC_CP16(ag[r] + k0, &As[r * 2048 + tid * 8]);
            ASYNC_CP16(bg[r] + k0, &Bs[r * 2048 + tid * 8]);
        }
        __syncthreads();
#pragma unroll
        for (int ks = 0; ks < 2; ++ks) {
            const int cbase = ks * 4 + quad;
            bf16x8 af[4], bf[4];
#pragma unroll
            for (int i = 0; i < 4; ++i) {
                int rla = wm * 64 + i * 16 + (lane & 15);
                int rlb = wn * 64 + i * 16 + (lane & 15);
                af[i] = *(const bf16x8*)&As[rla * 64 + ((cbase ^ (rla & 7)) * 8)];
                bf[i] = *(const bf16x8*)&Bs[rlb * 64 + ((cbase ^ (rlb & 7)) * 8)];
            }
#pragma unroll
            for (int i = 0; i < 4; ++i)
#pragma unroll
                for (int j = 0; j < 4; ++j)
                    acc[i][j] = __builtin_amdgcn_mfma_f32_16x16x32_bf16(af[i], bf[j], acc[i][j], 0, 0, 0);
        }
        __syncthreads();
    }

    int mvalid = cnt - mtile * 128; if (mvalid > 128) mvalid = 128;
#pragma unroll
    for (int i = 0; i < 4; ++i)
#pragma unroll
        for (int r = 0; r < 4; ++r) {
            int rl = wm * 64 + i * 16 + quad * 4 + r;
            if (rl < mvalid) {
                int rowg = rowstart + rl;
                unsigned short* yrow = Ybuf + (size_t)rowg * DIM + ntile * 128 + wn * 64 + (lane & 15);
#pragma unroll
                for (int j = 0; j < 4; ++j)
                    yrow[j * 16] = f2bf(acc[i][j][r]);
            }
        }
}

// ---------------- combine: out[n] = w0*Y[row0] + w1*Y[row1] --------------
__global__ void combine_kernel(const unsigned short* __restrict__ Ybuf,
                               const int* __restrict__ row_of_a,
                               const float* __restrict__ a_w,
                               float* __restrict__ out) {
    int n = blockIdx.x, t = threadIdx.x;                 // 256 threads, DIM/4
    int r0 = row_of_a[2 * n], r1 = row_of_a[2 * n + 1];
    float w0 = a_w[2 * n], w1 = a_w[2 * n + 1];
    ushort4 y0 = *(const ushort4*)(Ybuf + (size_t)r0 * DIM + t * 4);
    ushort4 y1 = *(const ushort4*)(Ybuf + (size_t)r1 * DIM + t * 4);
    float4 o;
    o.x = w0 * bf2f(y0.x) + w1 * bf2f(y1.x);
    o.y = w0 * bf2f(y0.y) + w1 * bf2f(y1.y);
    o.z = w0 * bf2f(y0.z) + w1 * bf2f(y1.z);
    o.w = w0 * bf2f(y0.w) + w1 * bf2f(y1.w);
    *(float4*)(out + (size_t)n * DIM + t * 4) = o;
}

// ---------------- launch -------------------------------------------------
extern "C" void kernel_launch(void* const* d_in, const int* in_sizes, int n_in,
                              void* d_out, int out_size, void* d_ws, size_t ws_size,
                              hipStream_t stream) {
    const float* x  = (const float*)d_in[0];
    const float* Wg = (const float*)d_in[1];
    const float* W1 = (const float*)d_in[2];
    const float* W2 = (const float*)d_in[3];
    const float* W3 = (const float*)d_in[4];
    float* out = (float*)d_out;

    char* ws = (char*)d_ws;
    size_t off = 0;
    auto alloc = [&](size_t bytes) -> void* {
        void* p = ws + off;
        off = (off + bytes + 255) & ~(size_t)255;
        return p;
    };
    int*   counts      = (int*)alloc(NEXP * 4);
    int*   a_exp       = (int*)alloc(NROW * 4);
    int*   a_rank      = (int*)alloc(NROW * 4);
    float* a_w         = (float*)alloc(NROW * 4);
    int*   row_of_a    = (int*)alloc(NROW * 4);
    unsigned short* XG   = (unsigned short*)alloc((size_t)NROW * DIM * 2);
    unsigned short* Hbuf = (unsigned short*)alloc((size_t)NROW * HPAD * 2);
    unsigned short* W1b  = (unsigned short*)alloc((size_t)NEXP * HPAD * DIM * 2);
    unsigned short* W3b  = (unsigned short*)alloc((size_t)NEXP * HPAD * DIM * 2);
    unsigned short* W2b  = (unsigned short*)alloc((size_t)NEXP * DIM * HPAD * 2);
    // Ybuf bf16 (16.8 MB) aliases W1b (46.1 MB): W1b is dead once gemm1 completes.
    unsigned short* Ybuf = (unsigned short*)W1b;

    hipMemsetAsync(counts, 0, NEXP * 4, stream);

    prep_kernel<<<3 * C13BLK + NTOK / 4, 256, 0, stream>>>(
        x, Wg, W1, W2, W3, W1b, W2b, W3b, counts, a_exp, a_rank, a_w);
    gather_kernel<<<NROW, 256, 0, stream>>>(x, a_exp, a_rank, counts, XG, row_of_a);

    gemm1_kernel<<<dim3(HPAD / 64, 64, NEXP), 256, 0, stream>>>(
        XG, W1b, W3b, counts, Hbuf);
    gemm2_kernel<<<dim3(DIM / 128, 64, NEXP), 256, 0, stream>>>(
        Hbuf, W2b, counts, Ybuf);
    combine_kernel<<<NTOK, 256, 0, stream>>>(Ybuf, row_of_a, a_w, out);
}